// Round 4
// baseline (192.679 us; speedup 1.0000x reference)
//
#include <hip/hip_runtime.h>
#include <hip/hip_bf16.h>
#include <math.h>

#define BB 32
#define SS 128
#define DIN 17
#define DPT 64
#define DPA 128
#define DOU 64
#define NP 8256               // SS*(SS+1)/2
#define NROWS (BB * NP)       // 264192
#define NCHUNK (NROWS / 128)  // 2064
#define EPSF 1e-5f

typedef __hip_bfloat16 bf16;
typedef __attribute__((ext_vector_type(8))) short short8;
typedef __attribute__((ext_vector_type(16))) float f32x16;
typedef __attribute__((ext_vector_type(4))) float f32x4;
typedef __attribute__((ext_vector_type(4))) int int4v;
typedef __attribute__((ext_vector_type(4))) unsigned int uint4v;

#define MFMA32(a, b, c) __builtin_amdgcn_mfma_f32_32x32x16_bf16(a, b, c, 0, 0, 0)

__device__ __forceinline__ float bf2f(short u) {
    return __builtin_bit_cast(float, ((unsigned int)(unsigned short)u) << 16);
}

// v_permlane32_swap_b32: a' = {a.lo, b.lo}, b' = {a.hi, b.hi}
// (lane<32: a keeps own, b gets a[l+32]; lane>=32: a gets b[l-32], b keeps own)
__device__ __forceinline__ void plswap(unsigned int& a, unsigned int& b) {
    asm("v_permlane32_swap_b32 %0, %1" : "+v"(a), "+v"(b));
}
__device__ __forceinline__ unsigned int cvtpk(float lo, float hi) {
    unsigned int r;
    asm("v_cvt_pk_bf16_f32 %0, %1, %2" : "=v"(r) : "v"(lo), "v"(hi));
    return r;
}

// In-register transform of one 32x32 D-tile (per-lane 16 f32; ch_local(r) =
// 4*lhi + (r&3) + 8*(r>>2), col fixed) into two bf16x8 B-fragment octets:
// o0 = ch_local [8*lhi, 8*lhi+8), o1 = ch_local 16 + [8*lhi, 8*lhi+8).
__device__ __forceinline__ void xform(const f32x16& a, short8& o0, short8& o1) {
    unsigned int w[8];
#pragma unroll
    for (int j = 0; j < 8; ++j) w[j] = cvtpk(a[2 * j], a[2 * j + 1]);
    plswap(w[0], w[2]);
    plswap(w[1], w[3]);
    plswap(w[4], w[6]);
    plswap(w[5], w[7]);
    uint4v u0 = {w[0], w[1], w[2], w[3]};
    uint4v u1 = {w[4], w[5], w[6], w[7]};
    o0 = __builtin_bit_cast(short8, u0);
    o1 = __builtin_bit_cast(short8, u1);
}

// exact gelu via A&S 7.1.26 rational poly (|eps| <= 1.5e-7)
__device__ __forceinline__ float gelu_exact(float x) {
    float z = fabsf(x) * 0.7071067811865476f;
    float t = __builtin_amdgcn_rcpf(fmaf(0.3275911f, z, 1.0f));
    float p = fmaf(t, 1.061405429f, -1.453152027f);
    p = fmaf(t, p, 1.421413741f);
    p = fmaf(t, p, -0.284496736f);
    p = fmaf(t, p, 0.254829592f);
    p *= t;
    float e = __expf(-z * z);
    float erfz = 1.0f - p * e;
    float s = copysignf(erfz, x);
    return 0.5f * x * (1.0f + s);
}

// ---------------- K0: pair index table (i<<8 | j), tril order ----------------
__global__ void k_pairs(int* __restrict__ pairIJ) {
    int p = blockIdx.x * blockDim.x + threadIdx.x;
    if (p >= NP) return;
    int i = (int)((sqrtf(8.0f * (float)p + 1.0f) - 1.0f) * 0.5f);
    while ((i * (i + 1)) / 2 > p) --i;
    while (((i + 1) * (i + 2)) / 2 <= p) ++i;
    int j = p - (i * (i + 1)) / 2;
    pairIJ[p] = (i << 8) | j;
}

// ---- K0b: pack W^T into MFMA A-fragment layout ------------------------------
// frag[(mt*NS + s)*64 + lane][i] = W[k][m], k = s*16 + (lane>>5)*8 + i,
// m = mt*32 + (lane&31).  fragP1: wp1 (4mt,8s) | fragP2: wp2 | fragC2: wc2 (2mt,4s)
__global__ void k_pack(const float* __restrict__ wp1, const float* __restrict__ wp2,
                       const float* __restrict__ wc2, bf16* __restrict__ fragP1,
                       bf16* __restrict__ fragP2, bf16* __restrict__ fragC2) {
    int id = blockIdx.x * 256 + threadIdx.x;
    if (id < 16384) {
        int f = id >> 9, lane = (id >> 3) & 63, i = id & 7;
        int mt = f >> 3, s = f & 7;
        int k = s * 16 + (lane >> 5) * 8 + i;
        int m = mt * 32 + (lane & 31);
        fragP1[id] = __float2bfloat16(wp1[k * DPA + m]);
    } else if (id < 32768) {
        int rem = id - 16384;
        int f = rem >> 9, lane = (rem >> 3) & 63, i = rem & 7;
        int mt = f >> 3, s = f & 7;
        int k = s * 16 + (lane >> 5) * 8 + i;
        int m = mt * 32 + (lane & 31);
        fragP2[rem] = __float2bfloat16(wp2[k * DPA + m]);
    } else if (id < 36864) {
        int rem = id - 32768;
        int f = rem >> 9, lane = (rem >> 3) & 63, i = rem & 7;
        int mt = f >> 2, s = f & 3;
        int k = s * 16 + (lane >> 5) * 8 + i;
        int m = mt * 32 + (lane & 31);
        fragC2[rem] = __float2bfloat16(wc2[k * DOU + m]);
    }
}

// ---- K0c (after stats0): fold bn0 into wc1: fragC1 = pack((a0.*wc1)^T),
//      bc1p = d0 @ wc1 + bc1 -------------------------------------------------
__global__ void k_fold(const float* __restrict__ a0, const float* __restrict__ d0,
                       const float* __restrict__ wc1, const float* __restrict__ bc1,
                       bf16* __restrict__ fragC1, float* __restrict__ bc1p) {
    int id = blockIdx.x * 256 + threadIdx.x;
    if (id < 8192) {
        int f = id >> 9, lane = (id >> 3) & 63, i = id & 7;
        int mt = f >> 3, s = f & 7;
        int k = s * 16 + (lane >> 5) * 8 + i;
        int m = mt * 32 + (lane & 31);
        fragC1[id] = __float2bfloat16(a0[k] * wc1[k * DOU + m]);
    } else if (id < 8192 + 64) {
        int c = id - 8192;
        float s = bc1[c];
        for (int k = 0; k < DPA; ++k) s = fmaf(d0[k], wc1[k * DOU + c], s);
        bc1p[c] = s;
    }
}

// ---------------- K1: h = gelu(gelu(x@w1+b1)@w2+b2), bf16 out ----------------
__global__ void k_h(const float* __restrict__ x, const float* __restrict__ w1,
                    const float* __restrict__ b1, const float* __restrict__ w2,
                    const float* __restrict__ b2, bf16* __restrict__ h) {
    __shared__ float h1[4][DPT];
    int t = threadIdx.x;
    int rs = t >> 6;
    int c = t & 63;
    int r = blockIdx.x * 4 + rs;
    const float* xr = x + (size_t)r * DIN;
    float acc = b1[c];
#pragma unroll
    for (int k = 0; k < DIN; ++k) acc += xr[k] * w1[k * DPT + c];
    h1[rs][c] = gelu_exact(acc);
    __syncthreads();
    float acc2 = b2[c];
#pragma unroll
    for (int k = 0; k < DPT; ++k) acc2 += h1[rs][k] * w2[k * DPT + c];
    h[(size_t)r * DPT + c] = __float2bfloat16(gelu_exact(acc2));
}

// -------- K2: e0 = gelu(gelu(xij@wp1+bp1)@wp2+bp2); partial stats ------------
// Swapped GEMMs: D = W^T @ X^T. Per wave: 128ch x 32prow. GEMM1->GEMM2 handoff
// entirely in registers via cvt_pk + permlane32_swap. LDS only for X gather
// and output staging.
__global__ __launch_bounds__(256) void k_e0m(
    const bf16* __restrict__ h, const int* __restrict__ pairIJ,
    const short8* __restrict__ fragP1, const short8* __restrict__ fragP2,
    const float* __restrict__ bp1, const float* __restrict__ bp2,
    bf16* __restrict__ e0, float* __restrict__ part) {
    __shared__ __align__(16) char buf[32768];
    int t = threadIdx.x;
    int w = t >> 6, l = t & 63;
    int l31 = l & 31, lhi = l >> 5;
    int row0 = blockIdx.x * 128;
    int prow = w * 32 + l31;

    // gather xij chunk into swizzled LDS (16B units)
#pragma unroll
    for (int q = 0; q < 8; ++q) {
        int task = t + 256 * q;
        int rr = task >> 4, slot = task & 15;
        int n = row0 + rr;
        int b = n / NP, p = n - b * NP;
        int ij = pairIJ[p];
        int src = (slot < 8) ? (ij & 255) : (ij >> 8);
        int4v v = *(const int4v*)(h + (((size_t)(b * SS + src)) << 6) + ((slot & 7) << 3));
        *(int4v*)(buf + rr * 256 + ((slot * 16) ^ ((rr & 15) << 4))) = v;
    }
    __syncthreads();

    // ---- GEMM1: D1 = wp1^T @ X^T (acc[mt][r]: ch = mt*32+4*lhi+(r&3)+8*(r>>2))
    f32x16 acc[4];
#pragma unroll
    for (int mt = 0; mt < 4; ++mt)
#pragma unroll
        for (int g = 0; g < 4; ++g) {
            f32x4 bv = *(const f32x4*)(bp1 + mt * 32 + g * 8 + lhi * 4);
#pragma unroll
            for (int j = 0; j < 4; ++j) acc[mt][g * 4 + j] = bv[j];
        }
#pragma unroll
    for (int s = 0; s < 8; ++s) {
        short8 bx = *(const short8*)(buf + prow * 256 +
                                     (((s * 2 + lhi) * 16) ^ ((prow & 15) << 4)));
        acc[0] = MFMA32(fragP1[(0 * 8 + s) * 64 + l], bx, acc[0]);
        acc[1] = MFMA32(fragP1[(1 * 8 + s) * 64 + l], bx, acc[1]);
        acc[2] = MFMA32(fragP1[(2 * 8 + s) * 64 + l], bx, acc[2]);
        acc[3] = MFMA32(fragP1[(3 * 8 + s) * 64 + l], bx, acc[3]);
    }

    // gelu + in-register transform -> GEMM2 B-fragments
    short8 B2[8];
#pragma unroll
    for (int mt = 0; mt < 4; ++mt) {
#pragma unroll
        for (int r = 0; r < 16; ++r) acc[mt][r] = gelu_exact(acc[mt][r]);
        xform(acc[mt], B2[2 * mt], B2[2 * mt + 1]);
    }

    // ---- GEMM2: D2 = wp2^T @ mid^T
    f32x16 acc2[4];
#pragma unroll
    for (int mt = 0; mt < 4; ++mt)
#pragma unroll
        for (int g = 0; g < 4; ++g) {
            f32x4 bv = *(const f32x4*)(bp2 + mt * 32 + g * 8 + lhi * 4);
#pragma unroll
            for (int j = 0; j < 4; ++j) acc2[mt][g * 4 + j] = bv[j];
        }
#pragma unroll
    for (int s = 0; s < 8; ++s) {
        acc2[0] = MFMA32(fragP2[(0 * 8 + s) * 64 + l], B2[s], acc2[0]);
        acc2[1] = MFMA32(fragP2[(1 * 8 + s) * 64 + l], B2[s], acc2[1]);
        acc2[2] = MFMA32(fragP2[(2 * 8 + s) * 64 + l], B2[s], acc2[2]);
        acc2[3] = MFMA32(fragP2[(3 * 8 + s) * 64 + l], B2[s], acc2[3]);
    }
    __syncthreads();  // all X reads done; reuse buf for output staging

    // gelu + transform -> row-major octets, stage to LDS
#pragma unroll
    for (int mt = 0; mt < 4; ++mt) {
#pragma unroll
        for (int r = 0; r < 16; ++r) acc2[mt][r] = gelu_exact(acc2[mt][r]);
        short8 o0, o1;
        xform(acc2[mt], o0, o1);
        int slot0 = 4 * mt + lhi, slot1 = 4 * mt + 2 + lhi;
        *(short8*)(buf + prow * 256 + ((slot0 * 16) ^ ((prow & 15) << 4))) = o0;
        *(short8*)(buf + prow * 256 + ((slot1 * 16) ^ ((prow & 15) << 4))) = o1;
    }
    __syncthreads();

    // coalesced stores + per-thread channel-slice stats
    float sum[8], sq[8];
#pragma unroll
    for (int i = 0; i < 8; ++i) { sum[i] = 0.f; sq[i] = 0.f; }
    int slot = t & 15;
#pragma unroll
    for (int q = 0; q < 8; ++q) {
        int rr = (t >> 4) + 16 * q;
        short8 v = *(const short8*)(buf + rr * 256 + ((slot * 16) ^ ((rr & 15) << 4)));
        *(short8*)(e0 + (size_t)(row0 + rr) * DPA + slot * 8) = v;
#pragma unroll
        for (int i = 0; i < 8; ++i) {
            float f = bf2f(v[i]);
            sum[i] += f;
            sq[i] += f * f;
        }
    }
    __syncthreads();
    float* bb = (float*)buf;  // 256 threads x 16 floats = 16KB
#pragma unroll
    for (int i = 0; i < 8; ++i) {
        bb[t * 16 + i] = sum[i];
        bb[t * 16 + 8 + i] = sq[i];
    }
    __syncthreads();
    {
        int c = t & 127, isq = t >> 7;
        float s = 0.f;
#pragma unroll
        for (int g = 0; g < 16; ++g)
            s += bb[((c >> 3) + 16 * g) * 16 + isq * 8 + (c & 7)];
        part[(size_t)blockIdx.x * 256 + t] = s;
    }
}

// -------- stats finalize: a = g*rstd, d = be - mean*a ------------------------
__global__ void k_stats(const float* __restrict__ part, int nch, int nblk,
                        float* __restrict__ a, float* __restrict__ d,
                        const float* __restrict__ g, const float* __restrict__ be) {
    int c = blockIdx.x;
    __shared__ float ssum[256], ssq[256];
    float s = 0.f, q = 0.f;
    for (int bidx = threadIdx.x; bidx < nblk; bidx += 256) {
        s += part[(size_t)bidx * (2 * nch) + c];
        q += part[(size_t)bidx * (2 * nch) + nch + c];
    }
    ssum[threadIdx.x] = s;
    ssq[threadIdx.x] = q;
    __syncthreads();
    for (int w = 128; w > 0; w >>= 1) {
        if ((int)threadIdx.x < w) {
            ssum[threadIdx.x] += ssum[threadIdx.x + w];
            ssq[threadIdx.x] += ssq[threadIdx.x + w];
        }
        __syncthreads();
    }
    if (threadIdx.x == 0) {
        float mean = ssum[0] / (float)NROWS;
        float var = ssq[0] / (float)NROWS - mean * mean;
        float rstd = rsqrtf(var + EPSF);
        float aa = g[c] * rstd;
        a[c] = aa;
        d[c] = be[c] - mean * aa;
    }
}

// -------- K4: e1 = e0 @ wc1' + bc1' (bn0 folded); partial stats --------------
// B-fragments read directly from global e0 (row-major), no elementwise work.
__global__ __launch_bounds__(256) void k_e1m(
    const bf16* __restrict__ e0, const short8* __restrict__ fragC1,
    const float* __restrict__ bc1p, bf16* __restrict__ e1,
    float* __restrict__ part) {
    __shared__ __align__(16) char buf[16384];
    int t = threadIdx.x;
    int w = t >> 6, l = t & 63;
    int l31 = l & 31, lhi = l >> 5;
    int row0 = blockIdx.x * 128;
    int prow = w * 32 + l31;

    short8 B[8];
#pragma unroll
    for (int s = 0; s < 8; ++s)
        B[s] = *(const short8*)(e0 + (size_t)(row0 + prow) * DPA + s * 16 + lhi * 8);

    f32x16 acc[2];
#pragma unroll
    for (int mt = 0; mt < 2; ++mt)
#pragma unroll
        for (int g = 0; g < 4; ++g) {
            f32x4 bv = *(const f32x4*)(bc1p + mt * 32 + g * 8 + lhi * 4);
#pragma unroll
            for (int j = 0; j < 4; ++j) acc[mt][g * 4 + j] = bv[j];
        }
#pragma unroll
    for (int s = 0; s < 8; ++s) {
        acc[0] = MFMA32(fragC1[(0 * 8 + s) * 64 + l], B[s], acc[0]);
        acc[1] = MFMA32(fragC1[(1 * 8 + s) * 64 + l], B[s], acc[1]);
    }

#pragma unroll
    for (int mt = 0; mt < 2; ++mt) {
        short8 o0, o1;
        xform(acc[mt], o0, o1);
        int slot0 = 4 * mt + lhi, slot1 = 4 * mt + 2 + lhi;
        *(short8*)(buf + prow * 128 + ((slot0 * 16) ^ ((prow & 7) << 4))) = o0;
        *(short8*)(buf + prow * 128 + ((slot1 * 16) ^ ((prow & 7) << 4))) = o1;
    }
    __syncthreads();

    float sum[8], sq[8];
#pragma unroll
    for (int i = 0; i < 8; ++i) { sum[i] = 0.f; sq[i] = 0.f; }
    int slot = t & 7;
#pragma unroll
    for (int q = 0; q < 4; ++q) {
        int rr = (t >> 3) + 32 * q;
        short8 v = *(const short8*)(buf + rr * 128 + ((slot * 16) ^ ((rr & 7) << 4)));
        *(short8*)(e1 + (size_t)(row0 + rr) * DOU + slot * 8) = v;
#pragma unroll
        for (int i = 0; i < 8; ++i) {
            float f = bf2f(v[i]);
            sum[i] += f;
            sq[i] += f * f;
        }
    }
    __syncthreads();
    float* bb = (float*)buf;
#pragma unroll
    for (int i = 0; i < 8; ++i) {
        bb[t * 16 + i] = sum[i];
        bb[t * 16 + 8 + i] = sq[i];
    }
    __syncthreads();
    if (t < 128) {
        int c = t & 63, isq = t >> 6;
        float s = 0.f;
#pragma unroll
        for (int g = 0; g < 32; ++g)
            s += bb[((c >> 3) + 8 * g) * 16 + isq * 8 + (c & 7)];
        part[(size_t)blockIdx.x * 128 + t] = s;
    }
}

// -------- K6: e2 = gelu(bn1(e1)) @ wc2 + bc2; partial stats ------------------
__global__ __launch_bounds__(256) void k_e2m(
    const bf16* __restrict__ e1, const float* __restrict__ a1,
    const float* __restrict__ d1, const short8* __restrict__ fragC2,
    const float* __restrict__ bc2, bf16* __restrict__ e2,
    float* __restrict__ part) {
    __shared__ __align__(16) char buf[16384];
    int t = threadIdx.x;
    int w = t >> 6, l = t & 63;
    int l31 = l & 31, lhi = l >> 5;
    int row0 = blockIdx.x * 128;
    int prow = w * 32 + l31;

    short8 B[4];
#pragma unroll
    for (int s = 0; s < 4; ++s) {
        short8 raw = *(const short8*)(e1 + (size_t)(row0 + prow) * DOU + s * 16 + lhi * 8);
        int c0 = s * 16 + lhi * 8;
        f32x4 av0 = *(const f32x4*)(a1 + c0), av1 = *(const f32x4*)(a1 + c0 + 4);
        f32x4 dv0 = *(const f32x4*)(d1 + c0), dv1 = *(const f32x4*)(d1 + c0 + 4);
        float gg[8];
#pragma unroll
        for (int i = 0; i < 4; ++i) gg[i] = gelu_exact(fmaf(bf2f(raw[i]), av0[i], dv0[i]));
#pragma unroll
        for (int i = 0; i < 4; ++i) gg[4 + i] = gelu_exact(fmaf(bf2f(raw[4 + i]), av1[i], dv1[i]));
        uint4v u = {cvtpk(gg[0], gg[1]), cvtpk(gg[2], gg[3]),
                    cvtpk(gg[4], gg[5]), cvtpk(gg[6], gg[7])};
        B[s] = __builtin_bit_cast(short8, u);
    }

    f32x16 acc[2];
#pragma unroll
    for (int mt = 0; mt < 2; ++mt)
#pragma unroll
        for (int g = 0; g < 4; ++g) {
            f32x4 bv = *(const f32x4*)(bc2 + mt * 32 + g * 8 + lhi * 4);
#pragma unroll
            for (int j = 0; j < 4; ++j) acc[mt][g * 4 + j] = bv[j];
        }
#pragma unroll
    for (int s = 0; s < 4; ++s) {
        acc[0] = MFMA32(fragC2[(0 * 4 + s) * 64 + l], B[s], acc[0]);
        acc[1] = MFMA32(fragC2[(1 * 4 + s) * 64 + l], B[s], acc[1]);
    }

#pragma unroll
    for (int mt = 0; mt < 2; ++mt) {
        short8 o0, o1;
        xform(acc[mt], o0, o1);
        int slot0 = 4 * mt + lhi, slot1 = 4 * mt + 2 + lhi;
        *(short8*)(buf + prow * 128 + ((slot0 * 16) ^ ((prow & 7) << 4))) = o0;
        *(short8*)(buf + prow * 128 + ((slot1 * 16) ^ ((prow & 7) << 4))) = o1;
    }
    __syncthreads();

    float sum[8], sq[8];
#pragma unroll
    for (int i = 0; i < 8; ++i) { sum[i] = 0.f; sq[i] = 0.f; }
    int slot = t & 7;
#pragma unroll
    for (int q = 0; q < 4; ++q) {
        int rr = (t >> 3) + 32 * q;
        short8 v = *(const short8*)(buf + rr * 128 + ((slot * 16) ^ ((rr & 7) << 4)));
        *(short8*)(e2 + (size_t)(row0 + rr) * DOU + slot * 8) = v;
#pragma unroll
        for (int i = 0; i < 8; ++i) {
            float f = bf2f(v[i]);
            sum[i] += f;
            sq[i] += f * f;
        }
    }
    __syncthreads();
    float* bb = (float*)buf;
#pragma unroll
    for (int i = 0; i < 8; ++i) {
        bb[t * 16 + i] = sum[i];
        bb[t * 16 + 8 + i] = sq[i];
    }
    __syncthreads();
    if (t < 128) {
        int c = t & 63, isq = t >> 6;
        float s = 0.f;
#pragma unroll
        for (int g = 0; g < 32; ++g)
            s += bb[((c >> 3) + 8 * g) * 16 + isq * 8 + (c & 7)];
        part[(size_t)blockIdx.x * 128 + t] = s;
    }
}

// -------- K8: y[b,i,j,:] = y[b,j,i,:] = bn2(e2), vectorized ------------------
__global__ void k_out(const bf16* __restrict__ e2, const int* __restrict__ pairIJ,
                      const float* __restrict__ a2, const float* __restrict__ d2,
                      float* __restrict__ y) {
    int t = threadIdx.x;
    int n = blockIdx.x * 32 + (t >> 3);
    int c0 = (t & 7) * 8;
    int b = n / NP, p = n - b * NP;
    int ij = pairIJ[p];
    int ii = ij >> 8, jj = ij & 255;
    short8 raw = *(const short8*)(e2 + (size_t)n * DOU + c0);
    f32x4 aLo = *(const f32x4*)(a2 + c0), aHi = *(const f32x4*)(a2 + c0 + 4);
    f32x4 dLo = *(const f32x4*)(d2 + c0), dHi = *(const f32x4*)(d2 + c0 + 4);
    f32x4 v0, v1;
#pragma unroll
    for (int i = 0; i < 4; ++i) v0[i] = fmaf(bf2f(raw[i]), aLo[i], dLo[i]);
#pragma unroll
    for (int i = 0; i < 4; ++i) v1[i] = fmaf(bf2f(raw[4 + i]), aHi[i], dHi[i]);
    float* y1 = y + ((size_t)(b * SS + ii) * SS + jj) * DOU + c0;
    float* y2 = y + ((size_t)(b * SS + jj) * SS + ii) * DOU + c0;
    *(f32x4*)y1 = v0;
    *(f32x4*)(y1 + 4) = v1;
    *(f32x4*)y2 = v0;
    *(f32x4*)(y2 + 4) = v1;
}

extern "C" void kernel_launch(void* const* d_in, const int* in_sizes, int n_in,
                              void* d_out, int out_size, void* d_ws, size_t ws_size,
                              hipStream_t stream) {
    const float* x   = (const float*)d_in[0];
    const float* w1  = (const float*)d_in[1];
    const float* b1  = (const float*)d_in[2];
    const float* w2  = (const float*)d_in[3];
    const float* b2  = (const float*)d_in[4];
    const float* wp1 = (const float*)d_in[5];
    const float* bp1 = (const float*)d_in[6];
    const float* wp2 = (const float*)d_in[7];
    const float* bp2 = (const float*)d_in[8];
    const float* g0  = (const float*)d_in[9];
    const float* be0 = (const float*)d_in[10];
    const float* wc1 = (const float*)d_in[11];
    const float* bc1 = (const float*)d_in[12];
    const float* g1  = (const float*)d_in[13];
    const float* be1 = (const float*)d_in[14];
    const float* wc2 = (const float*)d_in[15];
    const float* bc2 = (const float*)d_in[16];
    const float* g2  = (const float*)d_in[17];
    const float* be2 = (const float*)d_in[18];

    char* ws = (char*)d_ws;
    const size_t OFF_PAIR   = 0;          // 33024
    const size_t OFF_H      = 33280;      // 524288
    const size_t OFF_PART   = 557568;     // 2064*256*4 = 2113536
    const size_t OFF_FRAGP1 = 2671104;    // 32768
    const size_t OFF_FRAGP2 = 2703872;    // 32768
    const size_t OFF_FRAGC1 = 2736640;    // 16384
    const size_t OFF_FRAGC2 = 2753024;    // 8192
    const size_t OFF_BC1P   = 2761216;    // 256
    const size_t OFF_A0 = 2761472, OFF_D0 = 2761984;
    const size_t OFF_A1 = 2762496, OFF_D1 = 2762752;
    const size_t OFF_A2 = 2763008, OFF_D2 = 2763264;
    const size_t OFF_E2 = 2763520;        // 33816576

    int*   pairIJ = (int*)(ws + OFF_PAIR);
    bf16*  h      = (bf16*)(ws + OFF_H);
    float* part   = (float*)(ws + OFF_PART);
    bf16*  fragP1 = (bf16*)(ws + OFF_FRAGP1);
    bf16*  fragP2 = (bf16*)(ws + OFF_FRAGP2);
    bf16*  fragC1 = (bf16*)(ws + OFF_FRAGC1);
    bf16*  fragC2 = (bf16*)(ws + OFF_FRAGC2);
    float* bc1p   = (float*)(ws + OFF_BC1P);
    float* a0 = (float*)(ws + OFF_A0);
    float* d0 = (float*)(ws + OFF_D0);
    float* a1 = (float*)(ws + OFF_A1);
    float* d1 = (float*)(ws + OFF_D1);
    float* a2 = (float*)(ws + OFF_A2);
    float* d2 = (float*)(ws + OFF_D2);
    bf16*  e2 = (bf16*)(ws + OFF_E2);

    bf16* e0 = (bf16*)d_out;
    bf16* e1 = (bf16*)((char*)d_out + (size_t)NROWS * DPA * sizeof(bf16));
    float* y = (float*)d_out;

    k_pairs<<<(NP + 255) / 256, 256, 0, stream>>>(pairIJ);
    k_pack<<<144, 256, 0, stream>>>(wp1, wp2, wc2, fragP1, fragP2, fragC2);
    k_h<<<(BB * SS) / 4, 256, 0, stream>>>(x, w1, b1, w2, b2, h);
    k_e0m<<<NCHUNK, 256, 0, stream>>>(h, pairIJ, (const short8*)fragP1,
                                      (const short8*)fragP2, bp1, bp2, e0, part);
    k_stats<<<DPA, 256, 0, stream>>>(part, DPA, NCHUNK, a0, d0, g0, be0);
    k_fold<<<33, 256, 0, stream>>>(a0, d0, wc1, bc1, fragC1, bc1p);
    k_e1m<<<NCHUNK, 256, 0, stream>>>(e0, (const short8*)fragC1, bc1p, e1, part);
    k_stats<<<DOU, 256, 0, stream>>>(part, DOU, NCHUNK, a1, d1, g1, be1);
    k_e2m<<<NCHUNK, 256, 0, stream>>>(e1, a1, d1, (const short8*)fragC2, bc2, e2, part);
    k_stats<<<DOU, 256, 0, stream>>>(part, DOU, NCHUNK, a2, d2, g2, be2);
    k_out<<<NROWS / 32, 256, 0, stream>>>(e2, pairIJ, a2, d2, y);
}

// Round 5
// 158.053 us; speedup vs baseline: 1.2191x; 1.2191x over previous
//
#include <hip/hip_runtime.h>
#include <hip/hip_bf16.h>
#include <math.h>

#define BB 32
#define SS 128
#define DIN 17
#define DPT 64
#define DPA 128
#define DOU 64
#define NP 8256               // SS*(SS+1)/2
#define NROWS (BB * NP)       // 264192
#define NCHUNK (NROWS / 128)  // 2064
#define EPSF 1e-5f

typedef __hip_bfloat16 bf16;
typedef __attribute__((ext_vector_type(8))) short short8;
typedef __attribute__((ext_vector_type(16))) float f32x16;
typedef __attribute__((ext_vector_type(4))) float f32x4;
typedef __attribute__((ext_vector_type(4))) int int4v;
typedef __attribute__((ext_vector_type(4))) unsigned int uint4v;

#define MFMA32(a, b, c) __builtin_amdgcn_mfma_f32_32x32x16_bf16(a, b, c, 0, 0, 0)

__device__ __forceinline__ float bf2f(short u) {
    return __builtin_bit_cast(float, ((unsigned int)(unsigned short)u) << 16);
}

// v_permlane32_swap_b32: a' = {a.lo, b.lo}, b' = {a.hi, b.hi}
__device__ __forceinline__ void plswap(unsigned int& a, unsigned int& b) {
    asm("v_permlane32_swap_b32 %0, %1" : "+v"(a), "+v"(b));
}
__device__ __forceinline__ unsigned int cvtpk(float lo, float hi) {
    unsigned int r;
    asm("v_cvt_pk_bf16_f32 %0, %1, %2" : "=v"(r) : "v"(lo), "v"(hi));
    return r;
}

// Transform one 32x32 swapped-D tile (lane: col=prow, ch_local(r)=4*lhi+(r&3)+8*(r>>2))
// into two bf16x8 B-fragment octets: o0 = ch_local [8lhi,8lhi+8), o1 = +16.
__device__ __forceinline__ void xform(const f32x16& a, short8& o0, short8& o1) {
    unsigned int w[8];
#pragma unroll
    for (int j = 0; j < 8; ++j) w[j] = cvtpk(a[2 * j], a[2 * j + 1]);
    plswap(w[0], w[2]);
    plswap(w[1], w[3]);
    plswap(w[4], w[6]);
    plswap(w[5], w[7]);
    uint4v u0 = {w[0], w[1], w[2], w[3]};
    uint4v u1 = {w[4], w[5], w[6], w[7]};
    o0 = __builtin_bit_cast(short8, u0);
    o1 = __builtin_bit_cast(short8, u1);
}

// tanh-form gelu, branchless, |err| <= ~3e-4 relative (bf16-safe): ~8 VALU ops
__device__ __forceinline__ float gelu_exact(float x) {
    float x2 = x * x;
    float m = fmaf(0.0356774081f, x2, 0.7978845608f);
    float e = __expf(2.0f * x * m);
    float r = __builtin_amdgcn_rcpf(e + 1.0f);
    return fmaf(-x, r, x);  // x*(1 - 1/(e^{2y}+1)) ... = 0.5x(1+tanh(y))
}

// ---------------- K0: pair index table (i<<8 | j), tril order ----------------
__global__ void k_pairs(int* __restrict__ pairIJ) {
    int p = blockIdx.x * blockDim.x + threadIdx.x;
    if (p >= NP) return;
    int i = (int)((sqrtf(8.0f * (float)p + 1.0f) - 1.0f) * 0.5f);
    while ((i * (i + 1)) / 2 > p) --i;
    while (((i + 1) * (i + 2)) / 2 <= p) ++i;
    int j = p - (i * (i + 1)) / 2;
    pairIJ[p] = (i << 8) | j;
}

// ---- K0b: pack W^T into MFMA A-fragment layout ------------------------------
// frag[(mt*NS + s)*64 + lane][i] = W[k][m], k = s*16 + (lane>>5)*8 + i,
// m = mt*32 + (lane&31).
__global__ void k_pack(const float* __restrict__ wp1, const float* __restrict__ wp2,
                       const float* __restrict__ wc2, bf16* __restrict__ fragP1,
                       bf16* __restrict__ fragP2, bf16* __restrict__ fragC2) {
    int id = blockIdx.x * 256 + threadIdx.x;
    if (id < 16384) {
        int f = id >> 9, lane = (id >> 3) & 63, i = id & 7;
        int mt = f >> 3, s = f & 7;
        int k = s * 16 + (lane >> 5) * 8 + i;
        int m = mt * 32 + (lane & 31);
        fragP1[id] = __float2bfloat16(wp1[k * DPA + m]);
    } else if (id < 32768) {
        int rem = id - 16384;
        int f = rem >> 9, lane = (rem >> 3) & 63, i = rem & 7;
        int mt = f >> 3, s = f & 7;
        int k = s * 16 + (lane >> 5) * 8 + i;
        int m = mt * 32 + (lane & 31);
        fragP2[rem] = __float2bfloat16(wp2[k * DPA + m]);
    } else if (id < 36864) {
        int rem = id - 32768;
        int f = rem >> 9, lane = (rem >> 3) & 63, i = rem & 7;
        int mt = f >> 2, s = f & 3;
        int k = s * 16 + (lane >> 5) * 8 + i;
        int m = mt * 32 + (lane & 31);
        fragC2[rem] = __float2bfloat16(wc2[k * DOU + m]);
    }
}

// ---- K0c (after stats0): fold bn0 into wc1 ----------------------------------
__global__ void k_fold(const float* __restrict__ a0, const float* __restrict__ d0,
                       const float* __restrict__ wc1, const float* __restrict__ bc1,
                       bf16* __restrict__ fragC1, float* __restrict__ bc1p) {
    int id = blockIdx.x * 256 + threadIdx.x;
    if (id < 8192) {
        int f = id >> 9, lane = (id >> 3) & 63, i = id & 7;
        int mt = f >> 3, s = f & 7;
        int k = s * 16 + (lane >> 5) * 8 + i;
        int m = mt * 32 + (lane & 31);
        fragC1[id] = __float2bfloat16(a0[k] * wc1[k * DOU + m]);
    } else if (id < 8192 + 64) {
        int c = id - 8192;
        float s = bc1[c];
        for (int k = 0; k < DPA; ++k) s = fmaf(d0[k], wc1[k * DOU + c], s);
        bc1p[c] = s;
    }
}

// ---------------- K1: h = gelu(gelu(x@w1+b1)@w2+b2), bf16 out ----------------
__global__ void k_h(const float* __restrict__ x, const float* __restrict__ w1,
                    const float* __restrict__ b1, const float* __restrict__ w2,
                    const float* __restrict__ b2, bf16* __restrict__ h) {
    __shared__ float h1[4][DPT];
    int t = threadIdx.x;
    int rs = t >> 6;
    int c = t & 63;
    int r = blockIdx.x * 4 + rs;
    const float* xr = x + (size_t)r * DIN;
    float acc = b1[c];
#pragma unroll
    for (int k = 0; k < DIN; ++k) acc += xr[k] * w1[k * DPT + c];
    h1[rs][c] = gelu_exact(acc);
    __syncthreads();
    float acc2 = b2[c];
#pragma unroll
    for (int k = 0; k < DPT; ++k) acc2 += h1[rs][k] * w2[k * DPT + c];
    h[(size_t)r * DPT + c] = __float2bfloat16(gelu_exact(acc2));
}

// -------- K2: e0 = gelu(gelu(xij@wp1+bp1)@wp2+bp2); partial stats ------------
// Swapped GEMMs D = W^T @ X^T; X read DIRECTLY from h (L2-resident, no gather
// LDS/barrier). Weights: fragP1 mt0,1 in REGISTERS; fragP1 mt2,3 + fragP2 in
// LDS (conflict-free ds_read_b128). Output staged in LDS (overlay fragP2).
__global__ __launch_bounds__(256, 2) void k_e0m(
    const bf16* __restrict__ h, const int* __restrict__ pairIJ,
    const short8* __restrict__ fragP1, const short8* __restrict__ fragP2,
    const float* __restrict__ bp1, const float* __restrict__ bp2,
    bf16* __restrict__ e0, float* __restrict__ part) {
    // [0,16K): fragP1 mt2,3 | [16K,48K): fragP2, later overlay: stage/stats
    __shared__ __align__(16) char lds[49152];
    int t = threadIdx.x;
    int w = t >> 6, l = t & 63;
    int l31 = l & 31, lhi = l >> 5;
    int row0 = blockIdx.x * 128;
    int prow = w * 32 + l31;

    // fill weight LDS: 3072 x 16B units (uniform branch per iteration)
    for (int u = t; u < 3072; u += 256) {
        short8 v = (u < 1024) ? fragP1[1024 + u] : fragP2[u - 1024];
        *(short8*)(lds + u * 16) = v;
    }

    // register-resident weights: fragP1 mt 0,1
    short8 Wa[16];
#pragma unroll
    for (int i = 0; i < 16; ++i) Wa[i] = fragP1[i * 64 + l];

    // B-fragments straight from h
    int n = row0 + prow;
    int b = n / NP, p = n - b * NP;
    int ij = pairIJ[p];
    const bf16* hj = h + (((size_t)(b * SS + (ij & 255))) << 6);
    const bf16* hi = h + (((size_t)(b * SS + (ij >> 8))) << 6);
    short8 bx[8];
#pragma unroll
    for (int s = 0; s < 4; ++s) {
        bx[s] = *(const short8*)(hj + s * 16 + lhi * 8);
        bx[s + 4] = *(const short8*)(hi + s * 16 + lhi * 8);
    }
    __syncthreads();  // weight LDS ready

    // ---- GEMM1: D1 = wp1^T @ X^T ----
    f32x16 acc[4];
#pragma unroll
    for (int mt = 0; mt < 4; ++mt)
#pragma unroll
        for (int g = 0; g < 4; ++g) {
            f32x4 bv = *(const f32x4*)(bp1 + mt * 32 + g * 8 + lhi * 4);
#pragma unroll
            for (int j = 0; j < 4; ++j) acc[mt][g * 4 + j] = bv[j];
        }
#pragma unroll
    for (int s = 0; s < 8; ++s) {
        short8 a2 = *(const short8*)(lds + (s * 64 + l) * 16);
        short8 a3 = *(const short8*)(lds + ((8 + s) * 64 + l) * 16);
        acc[0] = MFMA32(Wa[s], bx[s], acc[0]);
        acc[1] = MFMA32(Wa[8 + s], bx[s], acc[1]);
        acc[2] = MFMA32(a2, bx[s], acc[2]);
        acc[3] = MFMA32(a3, bx[s], acc[3]);
    }

    // gelu + in-register transform -> GEMM2 B-fragments
    short8 B2[8];
#pragma unroll
    for (int mt = 0; mt < 4; ++mt) {
#pragma unroll
        for (int r = 0; r < 16; ++r) acc[mt][r] = gelu_exact(acc[mt][r]);
        xform(acc[mt], B2[2 * mt], B2[2 * mt + 1]);
    }

    // ---- GEMM2: D2 = wp2^T @ mid^T (A from LDS) ----
    f32x16 acc2[4];
#pragma unroll
    for (int mt = 0; mt < 4; ++mt)
#pragma unroll
        for (int g = 0; g < 4; ++g) {
            f32x4 bv = *(const f32x4*)(bp2 + mt * 32 + g * 8 + lhi * 4);
#pragma unroll
            for (int j = 0; j < 4; ++j) acc2[mt][g * 4 + j] = bv[j];
        }
#pragma unroll
    for (int s = 0; s < 8; ++s) {
#pragma unroll
        for (int mt = 0; mt < 4; ++mt) {
            short8 a = *(const short8*)(lds + 16384 + ((mt * 8 + s) * 64 + l) * 16);
            acc2[mt] = MFMA32(a, B2[s], acc2[mt]);
        }
    }

    // gelu -> octets (registers only)
    short8 o[4][2];
#pragma unroll
    for (int mt = 0; mt < 4; ++mt) {
#pragma unroll
        for (int r = 0; r < 16; ++r) acc2[mt][r] = gelu_exact(acc2[mt][r]);
        xform(acc2[mt], o[mt][0], o[mt][1]);
    }
    __syncthreads();  // all fragP2 reads complete -> reuse as stage

    char* stage = lds + 16384;
#pragma unroll
    for (int mt = 0; mt < 4; ++mt) {
        int slot0 = 4 * mt + lhi, slot1 = 4 * mt + 2 + lhi;
        *(short8*)(stage + prow * 256 + ((slot0 * 16) ^ ((prow & 15) << 4))) = o[mt][0];
        *(short8*)(stage + prow * 256 + ((slot1 * 16) ^ ((prow & 15) << 4))) = o[mt][1];
    }
    __syncthreads();

    // coalesced stores + per-thread channel-slice stats
    float sum[8], sq[8];
#pragma unroll
    for (int i = 0; i < 8; ++i) { sum[i] = 0.f; sq[i] = 0.f; }
    int slot = t & 15;
#pragma unroll
    for (int q = 0; q < 8; ++q) {
        int rr = (t >> 4) + 16 * q;
        short8 v = *(const short8*)(stage + rr * 256 + ((slot * 16) ^ ((rr & 15) << 4)));
        *(short8*)(e0 + (size_t)(row0 + rr) * DPA + slot * 8) = v;
#pragma unroll
        for (int i = 0; i < 8; ++i) {
            float f = bf2f(v[i]);
            sum[i] += f;
            sq[i] += f * f;
        }
    }
    __syncthreads();
    float* bb = (float*)stage;  // 256 threads x 16 floats = 16KB
#pragma unroll
    for (int i = 0; i < 8; ++i) {
        bb[t * 16 + i] = sum[i];
        bb[t * 16 + 8 + i] = sq[i];
    }
    __syncthreads();
    {
        int c = t & 127, isq = t >> 7;
        float s = 0.f;
#pragma unroll
        for (int g = 0; g < 16; ++g)
            s += bb[((c >> 3) + 16 * g) * 16 + isq * 8 + (c & 7)];
        part[(size_t)blockIdx.x * 256 + t] = s;
    }
}

// -------- stats finalize: a = g*rstd, d = be - mean*a ------------------------
__global__ void k_stats(const float* __restrict__ part, int nch, int nblk,
                        float* __restrict__ a, float* __restrict__ d,
                        const float* __restrict__ g, const float* __restrict__ be) {
    int c = blockIdx.x;
    __shared__ float ssum[256], ssq[256];
    float s = 0.f, q = 0.f;
    for (int bidx = threadIdx.x; bidx < nblk; bidx += 256) {
        s += part[(size_t)bidx * (2 * nch) + c];
        q += part[(size_t)bidx * (2 * nch) + nch + c];
    }
    ssum[threadIdx.x] = s;
    ssq[threadIdx.x] = q;
    __syncthreads();
    for (int w = 128; w > 0; w >>= 1) {
        if ((int)threadIdx.x < w) {
            ssum[threadIdx.x] += ssum[threadIdx.x + w];
            ssq[threadIdx.x] += ssq[threadIdx.x + w];
        }
        __syncthreads();
    }
    if (threadIdx.x == 0) {
        float mean = ssum[0] / (float)NROWS;
        float var = ssq[0] / (float)NROWS - mean * mean;
        float rstd = rsqrtf(var + EPSF);
        float aa = g[c] * rstd;
        a[c] = aa;
        d[c] = be[c] - mean * aa;
    }
}

// -------- K4: e1 = e0 @ wc1' + bc1' (bn0 folded); partial stats --------------
__global__ __launch_bounds__(256) void k_e1m(
    const bf16* __restrict__ e0, const short8* __restrict__ fragC1,
    const float* __restrict__ bc1p, bf16* __restrict__ e1,
    float* __restrict__ part) {
    __shared__ __align__(16) char buf[16384];
    int t = threadIdx.x;
    int w = t >> 6, l = t & 63;
    int l31 = l & 31, lhi = l >> 5;
    int row0 = blockIdx.x * 128;
    int prow = w * 32 + l31;

    // explicit register residency for weights, then B loads
    short8 Wc[16];
#pragma unroll
    for (int i = 0; i < 16; ++i) Wc[i] = fragC1[i * 64 + l];
    short8 B[8];
#pragma unroll
    for (int s = 0; s < 8; ++s)
        B[s] = *(const short8*)(e0 + (size_t)(row0 + prow) * DPA + s * 16 + lhi * 8);

    f32x16 acc[2];
#pragma unroll
    for (int mt = 0; mt < 2; ++mt)
#pragma unroll
        for (int g = 0; g < 4; ++g) {
            f32x4 bv = *(const f32x4*)(bc1p + mt * 32 + g * 8 + lhi * 4);
#pragma unroll
            for (int j = 0; j < 4; ++j) acc[mt][g * 4 + j] = bv[j];
        }
#pragma unroll
    for (int s = 0; s < 8; ++s) {
        acc[0] = MFMA32(Wc[s], B[s], acc[0]);
        acc[1] = MFMA32(Wc[8 + s], B[s], acc[1]);
    }

#pragma unroll
    for (int mt = 0; mt < 2; ++mt) {
        short8 o0, o1;
        xform(acc[mt], o0, o1);
        int slot0 = 4 * mt + lhi, slot1 = 4 * mt + 2 + lhi;
        *(short8*)(buf + prow * 128 + ((slot0 * 16) ^ ((prow & 7) << 4))) = o0;
        *(short8*)(buf + prow * 128 + ((slot1 * 16) ^ ((prow & 7) << 4))) = o1;
    }
    __syncthreads();

    float sum[8], sq[8];
#pragma unroll
    for (int i = 0; i < 8; ++i) { sum[i] = 0.f; sq[i] = 0.f; }
    int slot = t & 7;
#pragma unroll
    for (int q = 0; q < 4; ++q) {
        int rr = (t >> 3) + 32 * q;
        short8 v = *(const short8*)(buf + rr * 128 + ((slot * 16) ^ ((rr & 7) << 4)));
        *(short8*)(e1 + (size_t)(row0 + rr) * DOU + slot * 8) = v;
#pragma unroll
        for (int i = 0; i < 8; ++i) {
            float f = bf2f(v[i]);
            sum[i] += f;
            sq[i] += f * f;
        }
    }
    __syncthreads();
    float* bb = (float*)buf;
#pragma unroll
    for (int i = 0; i < 8; ++i) {
        bb[t * 16 + i] = sum[i];
        bb[t * 16 + 8 + i] = sq[i];
    }
    __syncthreads();
    if (t < 128) {
        int c = t & 63, isq = t >> 6;
        float s = 0.f;
#pragma unroll
        for (int g = 0; g < 32; ++g)
            s += bb[((c >> 3) + 8 * g) * 16 + isq * 8 + (c & 7)];
        part[(size_t)blockIdx.x * 128 + t] = s;
    }
}

// -------- K6: e2 = gelu(bn1(e1)) @ wc2 + bc2; partial stats ------------------
__global__ __launch_bounds__(256) void k_e2m(
    const bf16* __restrict__ e1, const float* __restrict__ a1,
    const float* __restrict__ d1, const short8* __restrict__ fragC2,
    const float* __restrict__ bc2, bf16* __restrict__ e2,
    float* __restrict__ part) {
    __shared__ __align__(16) char buf[16384];
    int t = threadIdx.x;
    int w = t >> 6, l = t & 63;
    int l31 = l & 31, lhi = l >> 5;
    int row0 = blockIdx.x * 128;
    int prow = w * 32 + l31;

    short8 Wc[8];
#pragma unroll
    for (int s = 0; s < 8; ++s) Wc[s] = fragC2[s * 64 + l];

    short8 B[4];
#pragma unroll
    for (int s = 0; s < 4; ++s) {
        short8 raw = *(const short8*)(e1 + (size_t)(row0 + prow) * DOU + s * 16 + lhi * 8);
        int c0 = s * 16 + lhi * 8;
        f32x4 av0 = *(const f32x4*)(a1 + c0), av1 = *(const f32x4*)(a1 + c0 + 4);
        f32x4 dv0 = *(const f32x4*)(d1 + c0), dv1 = *(const f32x4*)(d1 + c0 + 4);
        float gg[8];
#pragma unroll
        for (int i = 0; i < 4; ++i) gg[i] = gelu_exact(fmaf(bf2f(raw[i]), av0[i], dv0[i]));
#pragma unroll
        for (int i = 0; i < 4; ++i) gg[4 + i] = gelu_exact(fmaf(bf2f(raw[4 + i]), av1[i], dv1[i]));
        uint4v u = {cvtpk(gg[0], gg[1]), cvtpk(gg[2], gg[3]),
                    cvtpk(gg[4], gg[5]), cvtpk(gg[6], gg[7])};
        B[s] = __builtin_bit_cast(short8, u);
    }

    f32x16 acc[2];
#pragma unroll
    for (int mt = 0; mt < 2; ++mt)
#pragma unroll
        for (int g = 0; g < 4; ++g) {
            f32x4 bv = *(const f32x4*)(bc2 + mt * 32 + g * 8 + lhi * 4);
#pragma unroll
            for (int j = 0; j < 4; ++j) acc[mt][g * 4 + j] = bv[j];
        }
#pragma unroll
    for (int s = 0; s < 4; ++s) {
        acc[0] = MFMA32(Wc[s], B[s], acc[0]);
        acc[1] = MFMA32(Wc[4 + s], B[s], acc[1]);
    }

#pragma unroll
    for (int mt = 0; mt < 2; ++mt) {
        short8 o0, o1;
        xform(acc[mt], o0, o1);
        int slot0 = 4 * mt + lhi, slot1 = 4 * mt + 2 + lhi;
        *(short8*)(buf + prow * 128 + ((slot0 * 16) ^ ((prow & 7) << 4))) = o0;
        *(short8*)(buf + prow * 128 + ((slot1 * 16) ^ ((prow & 7) << 4))) = o1;
    }
    __syncthreads();

    float sum[8], sq[8];
#pragma unroll
    for (int i = 0; i < 8; ++i) { sum[i] = 0.f; sq[i] = 0.f; }
    int slot = t & 7;
#pragma unroll
    for (int q = 0; q < 4; ++q) {
        int rr = (t >> 3) + 32 * q;
        short8 v = *(const short8*)(buf + rr * 128 + ((slot * 16) ^ ((rr & 7) << 4)));
        *(short8*)(e2 + (size_t)(row0 + rr) * DOU + slot * 8) = v;
#pragma unroll
        for (int i = 0; i < 8; ++i) {
            float f = bf2f(v[i]);
            sum[i] += f;
            sq[i] += f * f;
        }
    }
    __syncthreads();
    float* bb = (float*)buf;
#pragma unroll
    for (int i = 0; i < 8; ++i) {
        bb[t * 16 + i] = sum[i];
        bb[t * 16 + 8 + i] = sq[i];
    }
    __syncthreads();
    if (t < 128) {
        int c = t & 63, isq = t >> 6;
        float s = 0.f;
#pragma unroll
        for (int g = 0; g < 32; ++g)
            s += bb[((c >> 3) + 8 * g) * 16 + isq * 8 + (c & 7)];
        part[(size_t)blockIdx.x * 128 + t] = s;
    }
}

// -------- K8: y[b,i,j,:] = y[b,j,i,:] = bn2(e2), vectorized ------------------
__global__ void k_out(const bf16* __restrict__ e2, const int* __restrict__ pairIJ,
                      const float* __restrict__ a2, const float* __restrict__ d2,
                      float* __restrict__ y) {
    int t = threadIdx.x;
    int n = blockIdx.x * 32 + (t >> 3);
    int c0 = (t & 7) * 8;
    int b = n / NP, p = n - b * NP;
    int ij = pairIJ[p];
    int ii = ij >> 8, jj = ij & 255;
    short8 raw = *(const short8*)(e2 + (size_t)n * DOU + c0);
    f32x4 aLo = *(const f32x4*)(a2 + c0), aHi = *(const f32x4*)(a2 + c0 + 4);
    f32x4 dLo = *(const f32x4*)(d2 + c0), dHi = *(const f32x4*)(d2 + c0 + 4);
    f32x4 v0, v1;
#pragma unroll
    for (int i = 0; i < 4; ++i) v0[i] = fmaf(bf2f(raw[i]), aLo[i], dLo[i]);
#pragma unroll
    for (int i = 0; i < 4; ++i) v1[i] = fmaf(bf2f(raw[4 + i]), aHi[i], dHi[i]);
    float* y1 = y + ((size_t)(b * SS + ii) * SS + jj) * DOU + c0;
    float* y2 = y + ((size_t)(b * SS + jj) * SS + ii) * DOU + c0;
    *(f32x4*)y1 = v0;
    *(f32x4*)(y1 + 4) = v1;
    *(f32x4*)y2 = v0;
    *(f32x4*)(y2 + 4) = v1;
}

extern "C" void kernel_launch(void* const* d_in, const int* in_sizes, int n_in,
                              void* d_out, int out_size, void* d_ws, size_t ws_size,
                              hipStream_t stream) {
    const float* x   = (const float*)d_in[0];
    const float* w1  = (const float*)d_in[1];
    const float* b1  = (const float*)d_in[2];
    const float* w2  = (const float*)d_in[3];
    const float* b2  = (const float*)d_in[4];
    const float* wp1 = (const float*)d_in[5];
    const float* bp1 = (const float*)d_in[6];
    const float* wp2 = (const float*)d_in[7];
    const float* bp2 = (const float*)d_in[8];
    const float* g0  = (const float*)d_in[9];
    const float* be0 = (const float*)d_in[10];
    const float* wc1 = (const float*)d_in[11];
    const float* bc1 = (const float*)d_in[12];
    const float* g1  = (const float*)d_in[13];
    const float* be1 = (const float*)d_in[14];
    const float* wc2 = (const float*)d_in[15];
    const float* bc2 = (const float*)d_in[16];
    const float* g2  = (const float*)d_in[17];
    const float* be2 = (const float*)d_in[18];

    char* ws = (char*)d_ws;
    const size_t OFF_PAIR   = 0;          // 33024
    const size_t OFF_H      = 33280;      // 524288
    const size_t OFF_PART   = 557568;     // 2064*256*4 = 2113536
    const size_t OFF_FRAGP1 = 2671104;    // 32768
    const size_t OFF_FRAGP2 = 2703872;    // 32768
    const size_t OFF_FRAGC1 = 2736640;    // 16384
    const size_t OFF_FRAGC2 = 2753024;    // 8192
    const size_t OFF_BC1P   = 2761216;    // 256
    const size_t OFF_A0 = 2761472, OFF_D0 = 2761984;
    const size_t OFF_A1 = 2762496, OFF_D1 = 2762752;
    const size_t OFF_A2 = 2763008, OFF_D2 = 2763264;
    const size_t OFF_E2 = 2763520;        // 33816576

    int*   pairIJ = (int*)(ws + OFF_PAIR);
    bf16*  h      = (bf16*)(ws + OFF_H);
    float* part   = (float*)(ws + OFF_PART);
    bf16*  fragP1 = (bf16*)(ws + OFF_FRAGP1);
    bf16*  fragP2 = (bf16*)(ws + OFF_FRAGP2);
    bf16*  fragC1 = (bf16*)(ws + OFF_FRAGC1);
    bf16*  fragC2 = (bf16*)(ws + OFF_FRAGC2);
    float* bc1p   = (float*)(ws + OFF_BC1P);
    float* a0 = (float*)(ws + OFF_A0);
    float* d0 = (float*)(ws + OFF_D0);
    float* a1 = (float*)(ws + OFF_A1);
    float* d1 = (float*)(ws + OFF_D1);
    float* a2 = (float*)(ws + OFF_A2);
    float* d2 = (float*)(ws + OFF_D2);
    bf16*  e2 = (bf16*)(ws + OFF_E2);

    bf16* e0 = (bf16*)d_out;
    bf16* e1 = (bf16*)((char*)d_out + (size_t)NROWS * DPA * sizeof(bf16));
    float* y = (float*)d_out;

    k_pairs<<<(NP + 255) / 256, 256, 0, stream>>>(pairIJ);
    k_pack<<<144, 256, 0, stream>>>(wp1, wp2, wc2, fragP1, fragP2, fragC2);
    k_h<<<(BB * SS) / 4, 256, 0, stream>>>(x, w1, b1, w2, b2, h);
    k_e0m<<<NCHUNK, 256, 0, stream>>>(h, pairIJ, (const short8*)fragP1,
                                      (const short8*)fragP2, bp1, bp2, e0, part);
    k_stats<<<DPA, 256, 0, stream>>>(part, DPA, NCHUNK, a0, d0, g0, be0);
    k_fold<<<33, 256, 0, stream>>>(a0, d0, wc1, bc1, fragC1, bc1p);
    k_e1m<<<NCHUNK, 256, 0, stream>>>(e0, (const short8*)fragC1, bc1p, e1, part);
    k_stats<<<DOU, 256, 0, stream>>>(part, DOU, NCHUNK, a1, d1, g1, be1);
    k_e2m<<<NCHUNK, 256, 0, stream>>>(e1, a1, d1, (const short8*)fragC2, bc2, e2, part);
    k_stats<<<DOU, 256, 0, stream>>>(part, DOU, NCHUNK, a2, d2, g2, be2);
    k_out<<<NROWS / 32, 256, 0, stream>>>(e2, pairIJ, a2, d2, y);
}